// Round 1
// baseline (137.218 us; speedup 1.0000x reference)
//
#include <hip/hip_runtime.h>

// Problem constants
#define BATCH 1024
#define C_CH  256
#define RR    49        // 7*7 spatial
#define SP    12544     // 256*49 elements per (b) in patch tensors; also FLAT
#define KVALID 625      // nonzero correlation outputs per batch
#define KPAD   640      // padded K for GEMM1
#define REP_N  1024

// Decode index u in [0,25) -> (i, d) with i,d in [0,7), i+d even.
// counts per i: 4,3,4,3,4,3,4 ; cum = {0,4,7,11,14,18,21,25}
__device__ __forceinline__ void dec25(int u, int& i, int& d) {
    int ii = 0;
    ii += (u >= 4);
    ii += (u >= 7);
    ii += (u >= 11);
    ii += (u >= 14);
    ii += (u >= 18);
    ii += (u >= 21);
    i = ii;
    const int cum[8] = {0,4,7,11,14,18,21,25};
    d = 2 * (u - cum[ii]) + (ii & 1);
}

// Map compact index a in [0,640) -> flat column index into W1's FLAT dim.
// a >= 625 maps to 0 (the corresponding x entry is zero, product is 0).
__device__ __forceinline__ int kflat_of(int a) {
    if (a >= KVALID) return 0;
    int ar = a / 25, ac = a % 25;
    int i, dy, j, dx;
    dec25(ar, i, dy);
    dec25(ac, j, dx);
    int pi = (dy + 16 - i) >> 1;
    int pj = (dx + 16 - j) >> 1;
    return (pi * 16 + pj) * 49 + i * 7 + j;
}

// ---------------------------------------------------------------------------
// Kernel 1: correlation -> compacted x [BATCH x KPAD] (zero-padded tail)
// One block per batch. Stage p1/p2 in LDS in 64-channel chunks.
// ---------------------------------------------------------------------------
__global__ __launch_bounds__(256) void corr_kernel(
    const float* __restrict__ p1, const float* __restrict__ p2,
    float* __restrict__ xo)
{
    __shared__ float s1[64 * RR];   // 12.25 KB
    __shared__ float s2[64 * RR];

    const int b = blockIdx.x;
    const int t = threadIdx.x;
    const float* P1 = p1 + (size_t)b * SP;
    const float* P2 = p2 + (size_t)b * SP;

    int ij[3], yx[3];
    #pragma unroll
    for (int s = 0; s < 3; ++s) {
        int a = t + s * 256;
        if (a < KVALID) {
            int ar = a / 25, ac = a % 25;
            int i, dy, j, dx;
            dec25(ar, i, dy);
            dec25(ac, j, dx);
            ij[s] = i * 7 + j;
            yx[s] = dy * 7 + dx;
        } else { ij[s] = 0; yx[s] = 0; }
    }

    float acc0 = 0.f, acc1 = 0.f, acc2 = 0.f;

    for (int cc = 0; cc < 4; ++cc) {
        __syncthreads();   // protect LDS from previous chunk's readers
        const float4* g1 = (const float4*)(P1 + cc * 64 * RR);
        const float4* g2 = (const float4*)(P2 + cc * 64 * RR);
        float4* l1 = (float4*)s1;
        float4* l2 = (float4*)s2;
        for (int i = t; i < (64 * RR) / 4; i += 256) { l1[i] = g1[i]; l2[i] = g2[i]; }
        __syncthreads();

        #pragma unroll 4
        for (int c = 0; c < 64; ++c) {
            const float* r1 = s1 + c * RR;
            const float* r2 = s2 + c * RR;
            acc0 = fmaf(r1[ij[0]], r2[yx[0]], acc0);
            acc1 = fmaf(r1[ij[1]], r2[yx[1]], acc1);
            acc2 = fmaf(r1[ij[2]], r2[yx[2]], acc2);
        }
    }

    float* row = xo + (size_t)b * KPAD;
    row[t]       = acc0;
    row[t + 256] = acc1;
    if (t < 128) row[t + 512] = (t < (KVALID - 512)) ? acc2 : 0.f;
}

// ---------------------------------------------------------------------------
// Kernels 2/3: tiled fp32 GEMM  Y[m,n] = relu( sum_k X[m,k]*W[n,k] + bias[n] )
// 64x64 tile, BK=32, 256 threads, 4x4 per-thread micro-tile.
// GATHER: W columns indexed through kflat_of (for W1).
// ---------------------------------------------------------------------------
template<bool GATHER, bool RELU>
__global__ __launch_bounds__(256) void gemm_kernel(
    const float* __restrict__ X, int ldx,
    const float* __restrict__ W, int ldw,
    const float* __restrict__ bias,
    float* __restrict__ Y, int N, int K)
{
    __shared__ float Xs[32][68];   // stride 68 floats: 16B-aligned rows, low conflicts
    __shared__ float Ws[32][68];
    __shared__ int   smap[KPAD];

    const int t      = threadIdx.x;
    const int m_base = blockIdx.y * 64;
    const int n_base = blockIdx.x * 64;

    if (GATHER) {
        for (int a = t; a < K; a += 256) smap[a] = kflat_of(a);
    }

    const int lm = t >> 2;          // 0..63 : row within tile for loads
    const int lk = (t & 3) * 8;     // 0,8,16,24 : k offset for loads
    const int tm = t >> 4;          // 0..15 : micro-tile row group
    const int tn = t & 15;          // 0..15 : micro-tile col group

    float acc[4][4] = {};

    for (int k0 = 0; k0 < K; k0 += 32) {
        __syncthreads();
        // Load X tile (transposed into LDS: Xs[k][m])
        {
            const float* src = X + (size_t)(m_base + lm) * ldx + k0 + lk;
            float4 v0 = *(const float4*)(src);
            float4 v1 = *(const float4*)(src + 4);
            Xs[lk + 0][lm] = v0.x; Xs[lk + 1][lm] = v0.y;
            Xs[lk + 2][lm] = v0.z; Xs[lk + 3][lm] = v0.w;
            Xs[lk + 4][lm] = v1.x; Xs[lk + 5][lm] = v1.y;
            Xs[lk + 6][lm] = v1.z; Xs[lk + 7][lm] = v1.w;
        }
        // Load W tile (transposed into LDS: Ws[k][n])
        if (GATHER) {
            const float* wrow = W + (size_t)(n_base + lm) * ldw;
            #pragma unroll
            for (int u = 0; u < 8; ++u) Ws[lk + u][lm] = wrow[smap[k0 + lk + u]];
        } else {
            const float* src = W + (size_t)(n_base + lm) * ldw + k0 + lk;
            float4 v0 = *(const float4*)(src);
            float4 v1 = *(const float4*)(src + 4);
            Ws[lk + 0][lm] = v0.x; Ws[lk + 1][lm] = v0.y;
            Ws[lk + 2][lm] = v0.z; Ws[lk + 3][lm] = v0.w;
            Ws[lk + 4][lm] = v1.x; Ws[lk + 5][lm] = v1.y;
            Ws[lk + 6][lm] = v1.z; Ws[lk + 7][lm] = v1.w;
        }
        __syncthreads();

        #pragma unroll
        for (int kk = 0; kk < 32; ++kk) {
            float4 av = *(const float4*)&Xs[kk][tm * 4];
            float4 bv = *(const float4*)&Ws[kk][tn * 4];
            acc[0][0] = fmaf(av.x, bv.x, acc[0][0]);
            acc[0][1] = fmaf(av.x, bv.y, acc[0][1]);
            acc[0][2] = fmaf(av.x, bv.z, acc[0][2]);
            acc[0][3] = fmaf(av.x, bv.w, acc[0][3]);
            acc[1][0] = fmaf(av.y, bv.x, acc[1][0]);
            acc[1][1] = fmaf(av.y, bv.y, acc[1][1]);
            acc[1][2] = fmaf(av.y, bv.z, acc[1][2]);
            acc[1][3] = fmaf(av.y, bv.w, acc[1][3]);
            acc[2][0] = fmaf(av.z, bv.x, acc[2][0]);
            acc[2][1] = fmaf(av.z, bv.y, acc[2][1]);
            acc[2][2] = fmaf(av.z, bv.z, acc[2][2]);
            acc[2][3] = fmaf(av.z, bv.w, acc[2][3]);
            acc[3][0] = fmaf(av.w, bv.x, acc[3][0]);
            acc[3][1] = fmaf(av.w, bv.y, acc[3][1]);
            acc[3][2] = fmaf(av.w, bv.z, acc[3][2]);
            acc[3][3] = fmaf(av.w, bv.w, acc[3][3]);
        }
    }

    // Epilogue: bias + relu + store
    #pragma unroll
    for (int i2 = 0; i2 < 4; ++i2) {
        int row = m_base + tm * 4 + i2;
        int col = n_base + tn * 4;
        float4 bv = *(const float4*)&bias[col];
        float4 v;
        v.x = acc[i2][0] + bv.x;
        v.y = acc[i2][1] + bv.y;
        v.z = acc[i2][2] + bv.z;
        v.w = acc[i2][3] + bv.w;
        if (RELU) {
            v.x = fmaxf(v.x, 0.f); v.y = fmaxf(v.y, 0.f);
            v.z = fmaxf(v.z, 0.f); v.w = fmaxf(v.w, 0.f);
        }
        *(float4*)&Y[(size_t)row * N + col] = v;
    }
}

// ---------------------------------------------------------------------------
// Kernel 4: out[b, :] = h2[b, :] @ W3.T + b3   (one block per batch row)
// ---------------------------------------------------------------------------
__global__ __launch_bounds__(256) void head_kernel(
    const float* __restrict__ h2, const float* __restrict__ W3,
    const float* __restrict__ b3, float* __restrict__ out)
{
    const int b = blockIdx.x;
    const int t = threadIdx.x;
    const float* row = h2 + (size_t)b * REP_N;

    float a0 = 0.f, a1 = 0.f, a2 = 0.f, a3 = 0.f;
    for (int k = t; k < REP_N; k += 256) {
        float x = row[k];
        a0 = fmaf(x, W3[k],             a0);
        a1 = fmaf(x, W3[REP_N + k],     a1);
        a2 = fmaf(x, W3[2 * REP_N + k], a2);
        a3 = fmaf(x, W3[3 * REP_N + k], a3);
    }
    #pragma unroll
    for (int off = 32; off > 0; off >>= 1) {
        a0 += __shfl_down(a0, off);
        a1 += __shfl_down(a1, off);
        a2 += __shfl_down(a2, off);
        a3 += __shfl_down(a3, off);
    }
    __shared__ float red[4][4];
    int wid = t >> 6, lane = t & 63;
    if (lane == 0) { red[wid][0] = a0; red[wid][1] = a1; red[wid][2] = a2; red[wid][3] = a3; }
    __syncthreads();
    if (t < 4) {
        out[b * 4 + t] = red[0][t] + red[1][t] + red[2][t] + red[3][t] + b3[t];
    }
}

extern "C" void kernel_launch(void* const* d_in, const int* in_sizes, int n_in,
                              void* d_out, int out_size, void* d_ws, size_t ws_size,
                              hipStream_t stream) {
    const float* p1 = (const float*)d_in[0];
    const float* p2 = (const float*)d_in[1];
    const float* W1 = (const float*)d_in[2];
    const float* b1 = (const float*)d_in[3];
    const float* W2 = (const float*)d_in[4];
    const float* b2 = (const float*)d_in[5];
    const float* W3 = (const float*)d_in[6];
    const float* b3 = (const float*)d_in[7];
    float* out = (float*)d_out;

    float* xo = (float*)d_ws;                          // 1024*640  = 2.62 MB
    float* h1 = xo + (size_t)BATCH * KPAD;             // 1024*1024 = 4.19 MB
    float* h2 = h1 + (size_t)BATCH * REP_N;            // 1024*1024 = 4.19 MB

    corr_kernel<<<BATCH, 256, 0, stream>>>(p1, p2, xo);
    gemm_kernel<true,  true><<<dim3(16, 16), 256, 0, stream>>>(xo, KPAD, W1, SP,    b1, h1, REP_N, KPAD);
    gemm_kernel<false, true><<<dim3(16, 16), 256, 0, stream>>>(h1, REP_N, W2, REP_N, b2, h2, REP_N, REP_N);
    head_kernel<<<BATCH, 256, 0, stream>>>(h2, W3, b3, out);
}

// Round 2
// 81.210 us; speedup vs baseline: 1.6897x; 1.6897x over previous
//
#include <hip/hip_runtime.h>

// Problem constants
#define BATCH 1024
#define RR    49        // 7*7 spatial
#define SP    12544     // 256*49 per-batch patch elems; also FLAT
#define KVALID 625      // nonzero correlation outputs per batch
#define KPAD   640      // padded K for GEMM1
#define REP_N  1024

typedef __attribute__((ext_vector_type(4))) float f32x4;
typedef __attribute__((ext_vector_type(8))) short s16x8;   // 8 bf16 (4 VGPRs)

// ---- bf16 split helpers (RNE) ----
__device__ __forceinline__ unsigned short f2bf_rne(float f) {
    unsigned int u = __float_as_uint(f);
    unsigned int r = u + 0x7FFFu + ((u >> 16) & 1u);
    return (unsigned short)(r >> 16);
}
__device__ __forceinline__ float bf2f(unsigned short h) {
    return __uint_as_float(((unsigned int)h) << 16);
}
__device__ __forceinline__ void split2(float v, unsigned short& h, unsigned short& l) {
    h = f2bf_rne(v);
    l = f2bf_rne(v - bf2f(h));
}

// Decode index u in [0,25) -> (i, d), i,d in [0,7), i+d even.
// counts per i: 4,3,4,3,4,3,4 ; cum(ii) = ceil(3.5*ii) = (7*ii+1)>>1
__device__ __forceinline__ void dec25(int u, int& i, int& d) {
    int ii = (u >= 4) + (u >= 7) + (u >= 11) + (u >= 14) + (u >= 18) + (u >= 21);
    int cum = (7 * ii + 1) >> 1;
    i = ii;
    d = 2 * (u - cum) + (ii & 1);
}

// Compact index a in [0,640) -> flat column into W1's FLAT dim (a>=625 unused).
__device__ __forceinline__ int kflat_of(int a) {
    int ar = a / 25, ac = a % 25;
    int i, dy, j, dx;
    dec25(ar, i, dy);
    dec25(ac, j, dx);
    int pi = (dy + 16 - i) >> 1;
    int pj = (dx + 16 - j) >> 1;
    return (pi * 16 + pj) * 49 + i * 7 + j;
}

// ---------------------------------------------------------------------------
// Kernel 1: correlation -> compacted x as bf16 hi/lo planes [BATCH x KPAD]
// ---------------------------------------------------------------------------
__global__ __launch_bounds__(256) void corr_kernel(
    const float* __restrict__ p1, const float* __restrict__ p2,
    unsigned short* __restrict__ xh, unsigned short* __restrict__ xl)
{
    __shared__ float s1[64 * RR];
    __shared__ float s2[64 * RR];

    const int b = blockIdx.x;
    const int t = threadIdx.x;
    const float* P1 = p1 + (size_t)b * SP;
    const float* P2 = p2 + (size_t)b * SP;

    int ij[3], yx[3];
    #pragma unroll
    for (int s = 0; s < 3; ++s) {
        int a = t + s * 256;
        if (a < KVALID) {
            int ar = a / 25, ac = a % 25;
            int i, dy, j, dx;
            dec25(ar, i, dy);
            dec25(ac, j, dx);
            ij[s] = i * 7 + j;
            yx[s] = dy * 7 + dx;
        } else { ij[s] = 0; yx[s] = 0; }
    }

    float acc0 = 0.f, acc1 = 0.f, acc2 = 0.f;

    for (int cc = 0; cc < 4; ++cc) {
        __syncthreads();
        const float4* g1 = (const float4*)(P1 + cc * 64 * RR);
        const float4* g2 = (const float4*)(P2 + cc * 64 * RR);
        float4* l1 = (float4*)s1;
        float4* l2 = (float4*)s2;
        for (int i = t; i < (64 * RR) / 4; i += 256) { l1[i] = g1[i]; l2[i] = g2[i]; }
        __syncthreads();

        #pragma unroll 4
        for (int c = 0; c < 64; ++c) {
            const float* r1 = s1 + c * RR;
            const float* r2 = s2 + c * RR;
            acc0 = fmaf(r1[ij[0]], r2[yx[0]], acc0);
            acc1 = fmaf(r1[ij[1]], r2[yx[1]], acc1);
            acc2 = fmaf(r1[ij[2]], r2[yx[2]], acc2);
        }
    }

    unsigned short h, l;
    unsigned short* rh = xh + (size_t)b * KPAD;
    unsigned short* rl = xl + (size_t)b * KPAD;
    split2(acc0, h, l); rh[t] = h;       rl[t] = l;
    split2(acc1, h, l); rh[t + 256] = h; rl[t + 256] = l;
    if (t < 128) {
        float v = (t < (KVALID - 512)) ? acc2 : 0.f;
        split2(v, h, l);
        rh[t + 512] = h; rl[t + 512] = l;
    }
}

// ---------------------------------------------------------------------------
// Prep: gather W1 columns + split  -> w1h/w1l [REP_N x KPAD]
// ---------------------------------------------------------------------------
__global__ __launch_bounds__(256) void prep_w1_kernel(
    const float* __restrict__ W1,
    unsigned short* __restrict__ wh, unsigned short* __restrict__ wl)
{
    int idx = blockIdx.x * 256 + threadIdx.x;   // over REP_N*KPAD
    int n = idx / KPAD, a = idx - n * KPAD;
    float v = 0.f;
    if (a < KVALID) v = W1[(size_t)n * SP + kflat_of(a)];
    unsigned short h, l;
    split2(v, h, l);
    wh[idx] = h; wl[idx] = l;
}

// ---------------------------------------------------------------------------
// Prep: split W2 -> w2h/w2l [REP_N x REP_N]
// ---------------------------------------------------------------------------
__global__ __launch_bounds__(256) void prep_w2_kernel(
    const float* __restrict__ W2,
    unsigned short* __restrict__ wh, unsigned short* __restrict__ wl)
{
    int idx = (blockIdx.x * 256 + threadIdx.x) * 4;
    float4 v = *(const float4*)&W2[idx];
    unsigned short h0, l0, h1, l1, h2, l2, h3, l3;
    split2(v.x, h0, l0); split2(v.y, h1, l1);
    split2(v.z, h2, l2); split2(v.w, h3, l3);
    ushort4 hv = make_ushort4(h0, h1, h2, h3);
    ushort4 lv = make_ushort4(l0, l1, l2, l3);
    *(ushort4*)&wh[idx] = hv;
    *(ushort4*)&wl[idx] = lv;
}

// ---------------------------------------------------------------------------
// MFMA GEMM: Y[m,n] = act( sum_k X[m,k]*W[n,k] + bias[n] )
// X,W given as bf16 hi/lo planes; products: hh + hl + lh (split-bf16 fp32).
// 64x64 tile, BK=64, 256 threads (4 waves), each wave a 32x32 sub-tile
// of 2x2 16x16x32 fragments. LDS rows padded to 72 bf16 (144 B).
// ---------------------------------------------------------------------------
#define MM(d, a, b) d = __builtin_amdgcn_mfma_f32_16x16x32_bf16(a, b, d, 0, 0, 0)

template<bool SPLIT_OUT>
__global__ __launch_bounds__(256) void gemm_mfma(
    const unsigned short* __restrict__ Xh, const unsigned short* __restrict__ Xl, int ldx,
    const unsigned short* __restrict__ Wh, const unsigned short* __restrict__ Wl, int ldw,
    const float* __restrict__ bias, int K,
    float* __restrict__ Yf, unsigned short* __restrict__ Yh, unsigned short* __restrict__ Yl,
    int ldy)
{
    __shared__ unsigned short As[2][64][72];   // [plane][m][k], 18.4 KB
    __shared__ unsigned short Bs[2][64][72];   // [plane][n][k]

    const int t = threadIdx.x;
    const int m_base = blockIdx.y * 64;
    const int n_base = blockIdx.x * 64;

    // staging: thread t handles row t>>2, two 8-ushort chunks at tc and tc+32
    const int trow = t >> 2;
    const int tc   = (t & 3) * 8;

    const unsigned short* xh_p = Xh + (size_t)(m_base + trow) * ldx + tc;
    const unsigned short* xl_p = Xl + (size_t)(m_base + trow) * ldx + tc;
    const unsigned short* wh_p = Wh + (size_t)(n_base + trow) * ldw + tc;
    const unsigned short* wl_p = Wl + (size_t)(n_base + trow) * ldw + tc;

    const int wv   = t >> 6;
    const int lane = t & 63;
    const int wr = (wv >> 1) * 32;   // wave row offset in tile
    const int wc = (wv & 1) * 32;    // wave col offset
    const int fr = lane & 15;        // fragment row/col
    const int fg = (lane >> 4) * 8;  // fragment k-offset

    f32x4 acc00 = {}, acc01 = {}, acc10 = {}, acc11 = {};

    for (int k0 = 0; k0 < K; k0 += 64) {
        // issue global loads early (regs, not LDS)
        s16x8 vxh0 = *(const s16x8*)(xh_p + k0);
        s16x8 vxh1 = *(const s16x8*)(xh_p + k0 + 32);
        s16x8 vxl0 = *(const s16x8*)(xl_p + k0);
        s16x8 vxl1 = *(const s16x8*)(xl_p + k0 + 32);
        s16x8 vwh0 = *(const s16x8*)(wh_p + k0);
        s16x8 vwh1 = *(const s16x8*)(wh_p + k0 + 32);
        s16x8 vwl0 = *(const s16x8*)(wl_p + k0);
        s16x8 vwl1 = *(const s16x8*)(wl_p + k0 + 32);
        __syncthreads();   // previous iteration's readers done
        *(s16x8*)&As[0][trow][tc]      = vxh0;
        *(s16x8*)&As[0][trow][tc + 32] = vxh1;
        *(s16x8*)&As[1][trow][tc]      = vxl0;
        *(s16x8*)&As[1][trow][tc + 32] = vxl1;
        *(s16x8*)&Bs[0][trow][tc]      = vwh0;
        *(s16x8*)&Bs[0][trow][tc + 32] = vwh1;
        *(s16x8*)&Bs[1][trow][tc]      = vwl0;
        *(s16x8*)&Bs[1][trow][tc + 32] = vwl1;
        __syncthreads();

        #pragma unroll
        for (int ks = 0; ks < 2; ++ks) {
            const int ko = ks * 32 + fg;
            s16x8 ah0 = *(const s16x8*)&As[0][wr + fr][ko];
            s16x8 ah1 = *(const s16x8*)&As[0][wr + 16 + fr][ko];
            s16x8 al0 = *(const s16x8*)&As[1][wr + fr][ko];
            s16x8 al1 = *(const s16x8*)&As[1][wr + 16 + fr][ko];
            s16x8 bh0 = *(const s16x8*)&Bs[0][wc + fr][ko];
            s16x8 bh1 = *(const s16x8*)&Bs[0][wc + 16 + fr][ko];
            s16x8 bl0 = *(const s16x8*)&Bs[1][wc + fr][ko];
            s16x8 bl1 = *(const s16x8*)&Bs[1][wc + 16 + fr][ko];

            MM(acc00, ah0, bh0); MM(acc00, ah0, bl0); MM(acc00, al0, bh0);
            MM(acc01, ah0, bh1); MM(acc01, ah0, bl1); MM(acc01, al0, bh1);
            MM(acc10, ah1, bh0); MM(acc10, ah1, bl0); MM(acc10, al1, bh0);
            MM(acc11, ah1, bh1); MM(acc11, ah1, bl1); MM(acc11, al1, bh1);
        }
    }

    // Epilogue. C/D layout: col = lane&15, row = 4*(lane>>4)+reg.
    const int arow = (lane >> 4) * 4;
    #pragma unroll
    for (int nf = 0; nf < 2; ++nf) {
        const int col = n_base + wc + nf * 16 + fr;
        const float bv = bias[col];
        #pragma unroll
        for (int mf = 0; mf < 2; ++mf) {
            const f32x4 a = (nf == 0) ? (mf == 0 ? acc00 : acc10)
                                      : (mf == 0 ? acc01 : acc11);
            #pragma unroll
            for (int r = 0; r < 4; ++r) {
                const int row = m_base + wr + mf * 16 + arow + r;
                float v = fmaxf(a[r] + bv, 0.f);   // both GEMMs have ReLU
                if (SPLIT_OUT) {
                    unsigned short h, l;
                    split2(v, h, l);
                    Yh[(size_t)row * ldy + col] = h;
                    Yl[(size_t)row * ldy + col] = l;
                } else {
                    Yf[(size_t)row * ldy + col] = v;
                }
            }
        }
    }
}

// ---------------------------------------------------------------------------
// Head: out[b,:] = h2[b,:] @ W3.T + b3
// ---------------------------------------------------------------------------
__global__ __launch_bounds__(256) void head_kernel(
    const float* __restrict__ h2, const float* __restrict__ W3,
    const float* __restrict__ b3, float* __restrict__ out)
{
    const int b = blockIdx.x;
    const int t = threadIdx.x;
    const float* row = h2 + (size_t)b * REP_N;

    float a0 = 0.f, a1 = 0.f, a2 = 0.f, a3 = 0.f;
    for (int k = t; k < REP_N; k += 256) {
        float x = row[k];
        a0 = fmaf(x, W3[k],             a0);
        a1 = fmaf(x, W3[REP_N + k],     a1);
        a2 = fmaf(x, W3[2 * REP_N + k], a2);
        a3 = fmaf(x, W3[3 * REP_N + k], a3);
    }
    #pragma unroll
    for (int off = 32; off > 0; off >>= 1) {
        a0 += __shfl_down(a0, off);
        a1 += __shfl_down(a1, off);
        a2 += __shfl_down(a2, off);
        a3 += __shfl_down(a3, off);
    }
    __shared__ float red[4][4];
    int wid = t >> 6, lane = t & 63;
    if (lane == 0) { red[wid][0] = a0; red[wid][1] = a1; red[wid][2] = a2; red[wid][3] = a3; }
    __syncthreads();
    if (t < 4) {
        out[b * 4 + t] = red[0][t] + red[1][t] + red[2][t] + red[3][t] + b3[t];
    }
}

extern "C" void kernel_launch(void* const* d_in, const int* in_sizes, int n_in,
                              void* d_out, int out_size, void* d_ws, size_t ws_size,
                              hipStream_t stream) {
    const float* p1 = (const float*)d_in[0];
    const float* p2 = (const float*)d_in[1];
    const float* W1 = (const float*)d_in[2];
    const float* b1 = (const float*)d_in[3];
    const float* W2 = (const float*)d_in[4];
    const float* b2 = (const float*)d_in[5];
    const float* W3 = (const float*)d_in[6];
    const float* b3 = (const float*)d_in[7];
    float* out = (float*)d_out;

    char* ws = (char*)d_ws;
    // region0 (x + w1 planes), later reused for h2 f32:
    unsigned short* xh  = (unsigned short*)(ws + 0);         // 1.31 MB
    unsigned short* xl  = (unsigned short*)(ws + 1310720);   // 1.31 MB
    unsigned short* w1h = (unsigned short*)(ws + 2621440);   // 1.31 MB
    unsigned short* w1l = (unsigned short*)(ws + 3932160);   // 1.31 MB
    float*          h2  = (float*)(ws + 0);                  // 4.19 MB (reuse after GEMM1)
    unsigned short* h1h = (unsigned short*)(ws + 5242880);   // 2.10 MB
    unsigned short* h1l = (unsigned short*)(ws + 7340032);   // 2.10 MB
    unsigned short* w2h = (unsigned short*)(ws + 9437184);   // 2.10 MB
    unsigned short* w2l = (unsigned short*)(ws + 11534336);  // 2.10 MB
    // total 13.63 MB

    corr_kernel<<<BATCH, 256, 0, stream>>>(p1, p2, xh, xl);
    prep_w1_kernel<<<(REP_N * KPAD) / 256, 256, 0, stream>>>(W1, w1h, w1l);
    prep_w2_kernel<<<(REP_N * REP_N) / (256 * 4), 256, 0, stream>>>(W2, w2h, w2l);

    // GEMM1: h1 = relu(x @ W1g.T + b1), split output planes
    gemm_mfma<true><<<dim3(16, 16), 256, 0, stream>>>(
        xh, xl, KPAD, w1h, w1l, KPAD, b1, KPAD,
        (float*)nullptr, h1h, h1l, REP_N);

    // GEMM2: h2 = relu(h1 @ W2.T + b2), f32 output (overwrites region0)
    gemm_mfma<false><<<dim3(16, 16), 256, 0, stream>>>(
        h1h, h1l, REP_N, w2h, w2l, REP_N, b2, REP_N,
        h2, (unsigned short*)nullptr, (unsigned short*)nullptr, REP_N);

    head_kernel<<<BATCH, 256, 0, stream>>>(h2, W3, b3, out);
}

// Round 3
// 68.225 us; speedup vs baseline: 2.0112x; 1.1903x over previous
//
#include <hip/hip_runtime.h>

// Problem constants
#define BATCH 1024
#define RR    49        // 7*7 spatial
#define SP    12544     // 256*49 per-batch patch elems; also FLAT
#define KVALID 625      // nonzero correlation outputs per batch
#define KPAD   640      // padded K for GEMM1
#define REP_N  1024

typedef __attribute__((ext_vector_type(4))) float f32x4;
typedef __attribute__((ext_vector_type(8))) short s16x8;   // 8 bf16 (4 VGPRs)

// ---- bf16 split helpers (RNE) ----
__device__ __forceinline__ unsigned short f2bf_rne(float f) {
    unsigned int u = __float_as_uint(f);
    unsigned int r = u + 0x7FFFu + ((u >> 16) & 1u);
    return (unsigned short)(r >> 16);
}
__device__ __forceinline__ float bf2f(unsigned short h) {
    return __uint_as_float(((unsigned int)h) << 16);
}
__device__ __forceinline__ void split2(float v, unsigned short& h, unsigned short& l) {
    h = f2bf_rne(v);
    l = f2bf_rne(v - bf2f(h));
}

// Decode index u in [0,25) -> (i, d), i,d in [0,7), i+d even.
__device__ __forceinline__ void dec25(int u, int& i, int& d) {
    int ii = (u >= 4) + (u >= 7) + (u >= 11) + (u >= 14) + (u >= 18) + (u >= 21);
    int cum = (7 * ii + 1) >> 1;
    i = ii;
    d = 2 * (u - cum) + (ii & 1);
}
// Encode (i,d) -> [0,25), inverse of dec25.
__device__ __forceinline__ int enc25(int i, int d) {
    return ((7 * i + 1) >> 1) + ((d - (i & 1)) >> 1);
}

// Compact index a in [0,640) -> flat column into W1's FLAT dim (a>=625 unused).
__device__ __forceinline__ int kflat_of(int a) {
    int ar = a / 25, ac = a % 25;
    int i, dy, j, dx;
    dec25(ar, i, dy);
    dec25(ac, j, dx);
    int pi = (dy + 16 - i) >> 1;
    int pj = (dx + 16 - j) >> 1;
    return (pi * 16 + pj) * 49 + i * 7 + j;
}

#define MM(d, a, b) d = __builtin_amdgcn_mfma_f32_16x16x32_bf16(a, b, d, 0, 0, 0)

// ---------------------------------------------------------------------------
// Kernel 1: correlation as per-batch Gram matrix via MFMA.
// G[s1,s2] = sum_c p1[c,s1]*p2[c,s2]; the 625 valid outputs are the entries
// with (i+dy) and (j+dx) both even. Split-bf16 (hh+hl+lh) for fp32 accuracy.
// One block = one batch; 64x64 output tile (49x49 used), K=256 in 4 chunks.
// ---------------------------------------------------------------------------
__global__ __launch_bounds__(256) void corr_gram_kernel(
    const float* __restrict__ p1, const float* __restrict__ p2,
    unsigned short* __restrict__ xh, unsigned short* __restrict__ xl)
{
    __shared__ unsigned short Ah[64][72];   // [spatial][channel-chunk] bf16-hi of p1^T
    __shared__ unsigned short Al[64][72];
    __shared__ unsigned short Bh[64][72];   // p2^T
    __shared__ unsigned short Bl[64][72];

    const int b = blockIdx.x;
    const int t = threadIdx.x;
    const float* P1 = p1 + (size_t)b * SP;
    const float* P2 = p2 + (size_t)b * SP;

    const int wv   = t >> 6;
    const int lane = t & 63;
    const int wr = (wv >> 1) * 32;   // wave row offset (s1)
    const int wc = (wv & 1) * 32;    // wave col offset (s2)
    const int fr = lane & 15;
    const int fg = (lane >> 4) * 8;

    f32x4 acc00 = {}, acc01 = {}, acc10 = {}, acc11 = {};

    for (int cc = 0; cc < 4; ++cc) {
        __syncthreads();   // previous chunk's MFMA readers done
        // Staging jobs: 2 tensors x 8 channel-groups x 49 spatial = 784 jobs.
        // Job: load 8 channels (stride 49 floats) at one spatial, split,
        // write one b128 per plane into the transposed LDS tile.
        for (int j = t; j < 784; j += 256) {
            const int isB = (j >= 392);
            const int jj = isB ? j - 392 : j;
            const float* P = isB ? P2 : P1;
            unsigned short* Hp = isB ? &Bh[0][0] : &Ah[0][0];
            unsigned short* Lp = isB ? &Bl[0][0] : &Al[0][0];
            const int cg = jj / 49;
            const int s  = jj - cg * 49;
            const float* src = P + (cc * 64 + cg * 8) * 49 + s;
            float v[8];
            #pragma unroll
            for (int i = 0; i < 8; ++i) v[i] = src[i * 49];
            s16x8 hv, lv;
            #pragma unroll
            for (int i = 0; i < 8; ++i) {
                unsigned short h, l;
                split2(v[i], h, l);
                hv[i] = (short)h; lv[i] = (short)l;
            }
            *(s16x8*)&Hp[s * 72 + cg * 8] = hv;
            *(s16x8*)&Lp[s * 72 + cg * 8] = lv;
        }
        __syncthreads();

        #pragma unroll
        for (int ks = 0; ks < 2; ++ks) {
            const int ko = ks * 32 + fg;
            s16x8 ah0 = *(const s16x8*)&Ah[wr + fr][ko];
            s16x8 ah1 = *(const s16x8*)&Ah[wr + 16 + fr][ko];
            s16x8 al0 = *(const s16x8*)&Al[wr + fr][ko];
            s16x8 al1 = *(const s16x8*)&Al[wr + 16 + fr][ko];
            s16x8 bh0 = *(const s16x8*)&Bh[wc + fr][ko];
            s16x8 bh1 = *(const s16x8*)&Bh[wc + 16 + fr][ko];
            s16x8 bl0 = *(const s16x8*)&Bl[wc + fr][ko];
            s16x8 bl1 = *(const s16x8*)&Bl[wc + 16 + fr][ko];

            MM(acc00, ah0, bh0); MM(acc00, ah0, bl0); MM(acc00, al0, bh0);
            MM(acc01, ah0, bh1); MM(acc01, ah0, bl1); MM(acc01, al0, bh1);
            MM(acc10, ah1, bh0); MM(acc10, ah1, bl0); MM(acc10, al1, bh0);
            MM(acc11, ah1, bh1); MM(acc11, ah1, bl1); MM(acc11, al1, bh1);
        }
    }

    // Zero the padded tail of x
    if (t < KPAD - KVALID) {
        xh[(size_t)b * KPAD + KVALID + t] = 0;
        xl[(size_t)b * KPAD + KVALID + t] = 0;
    }

    // Epilogue: C/D layout col = lane&15, row = 4*(lane>>4)+reg (verified R2).
    unsigned short* rh = xh + (size_t)b * KPAD;
    unsigned short* rl = xl + (size_t)b * KPAD;
    const int arow = (lane >> 4) * 4;
    #pragma unroll
    for (int nf = 0; nf < 2; ++nf) {
        const int n = wc + nf * 16 + fr;            // s2 = dy*7+dx
        #pragma unroll
        for (int mf = 0; mf < 2; ++mf) {
            const f32x4 a = (nf == 0) ? (mf == 0 ? acc00 : acc10)
                                      : (mf == 0 ? acc01 : acc11);
            #pragma unroll
            for (int r = 0; r < 4; ++r) {
                const int m = wr + mf * 16 + arow + r;   // s1 = i*7+j
                if (m < RR && n < RR) {
                    const int i  = m / 7, jj = m - i * 7;
                    const int dy = n / 7, dx = n - dy * 7;
                    if ((((i + dy) | (jj + dx)) & 1) == 0) {
                        const int aidx = enc25(i, dy) * 25 + enc25(jj, dx);
                        unsigned short h, l;
                        split2(a[r], h, l);
                        rh[aidx] = h; rl[aidx] = l;
                    }
                }
            }
        }
    }
}

// ---------------------------------------------------------------------------
// Prep: gather W1 columns + split  -> w1h/w1l [REP_N x KPAD]
// ---------------------------------------------------------------------------
__global__ __launch_bounds__(256) void prep_w1_kernel(
    const float* __restrict__ W1,
    unsigned short* __restrict__ wh, unsigned short* __restrict__ wl)
{
    int idx = blockIdx.x * 256 + threadIdx.x;   // over REP_N*KPAD
    int n = idx / KPAD, a = idx - n * KPAD;
    float v = 0.f;
    if (a < KVALID) v = W1[(size_t)n * SP + kflat_of(a)];
    unsigned short h, l;
    split2(v, h, l);
    wh[idx] = h; wl[idx] = l;
}

// ---------------------------------------------------------------------------
// Prep: split W2 -> w2h/w2l [REP_N x REP_N]
// ---------------------------------------------------------------------------
__global__ __launch_bounds__(256) void prep_w2_kernel(
    const float* __restrict__ W2,
    unsigned short* __restrict__ wh, unsigned short* __restrict__ wl)
{
    int idx = (blockIdx.x * 256 + threadIdx.x) * 4;
    float4 v = *(const float4*)&W2[idx];
    unsigned short h0, l0, h1, l1, h2, l2, h3, l3;
    split2(v.x, h0, l0); split2(v.y, h1, l1);
    split2(v.z, h2, l2); split2(v.w, h3, l3);
    ushort4 hv = make_ushort4(h0, h1, h2, h3);
    ushort4 lv = make_ushort4(l0, l1, l2, l3);
    *(ushort4*)&wh[idx] = hv;
    *(ushort4*)&wl[idx] = lv;
}

// ---------------------------------------------------------------------------
// MFMA GEMM: Y[m,n] = relu( sum_k X[m,k]*W[n,k] + bias[n] )
// X,W as bf16 hi/lo planes; products hh + hl + lh. 64x64 tile, BK=64,
// 4 waves (2x2), each wave 32x32 = 2x2 16x16x32 fragments.
// ---------------------------------------------------------------------------
template<bool SPLIT_OUT>
__global__ __launch_bounds__(256) void gemm_mfma(
    const unsigned short* __restrict__ Xh, const unsigned short* __restrict__ Xl, int ldx,
    const unsigned short* __restrict__ Wh, const unsigned short* __restrict__ Wl, int ldw,
    const float* __restrict__ bias, int K,
    float* __restrict__ Yf, unsigned short* __restrict__ Yh, unsigned short* __restrict__ Yl,
    int ldy)
{
    __shared__ unsigned short As[2][64][72];
    __shared__ unsigned short Bs[2][64][72];

    const int t = threadIdx.x;
    const int m_base = blockIdx.y * 64;
    const int n_base = blockIdx.x * 64;

    const int trow = t >> 2;
    const int tc   = (t & 3) * 8;

    const unsigned short* xh_p = Xh + (size_t)(m_base + trow) * ldx + tc;
    const unsigned short* xl_p = Xl + (size_t)(m_base + trow) * ldx + tc;
    const unsigned short* wh_p = Wh + (size_t)(n_base + trow) * ldw + tc;
    const unsigned short* wl_p = Wl + (size_t)(n_base + trow) * ldw + tc;

    const int wv   = t >> 6;
    const int lane = t & 63;
    const int wr = (wv >> 1) * 32;
    const int wc = (wv & 1) * 32;
    const int fr = lane & 15;
    const int fg = (lane >> 4) * 8;

    f32x4 acc00 = {}, acc01 = {}, acc10 = {}, acc11 = {};

    for (int k0 = 0; k0 < K; k0 += 64) {
        s16x8 vxh0 = *(const s16x8*)(xh_p + k0);
        s16x8 vxh1 = *(const s16x8*)(xh_p + k0 + 32);
        s16x8 vxl0 = *(const s16x8*)(xl_p + k0);
        s16x8 vxl1 = *(const s16x8*)(xl_p + k0 + 32);
        s16x8 vwh0 = *(const s16x8*)(wh_p + k0);
        s16x8 vwh1 = *(const s16x8*)(wh_p + k0 + 32);
        s16x8 vwl0 = *(const s16x8*)(wl_p + k0);
        s16x8 vwl1 = *(const s16x8*)(wl_p + k0 + 32);
        __syncthreads();
        *(s16x8*)&As[0][trow][tc]      = vxh0;
        *(s16x8*)&As[0][trow][tc + 32] = vxh1;
        *(s16x8*)&As[1][trow][tc]      = vxl0;
        *(s16x8*)&As[1][trow][tc + 32] = vxl1;
        *(s16x8*)&Bs[0][trow][tc]      = vwh0;
        *(s16x8*)&Bs[0][trow][tc + 32] = vwh1;
        *(s16x8*)&Bs[1][trow][tc]      = vwl0;
        *(s16x8*)&Bs[1][trow][tc + 32] = vwl1;
        __syncthreads();

        #pragma unroll
        for (int ks = 0; ks < 2; ++ks) {
            const int ko = ks * 32 + fg;
            s16x8 ah0 = *(const s16x8*)&As[0][wr + fr][ko];
            s16x8 ah1 = *(const s16x8*)&As[0][wr + 16 + fr][ko];
            s16x8 al0 = *(const s16x8*)&As[1][wr + fr][ko];
            s16x8 al1 = *(const s16x8*)&As[1][wr + 16 + fr][ko];
            s16x8 bh0 = *(const s16x8*)&Bs[0][wc + fr][ko];
            s16x8 bh1 = *(const s16x8*)&Bs[0][wc + 16 + fr][ko];
            s16x8 bl0 = *(const s16x8*)&Bs[1][wc + fr][ko];
            s16x8 bl1 = *(const s16x8*)&Bs[1][wc + 16 + fr][ko];

            MM(acc00, ah0, bh0); MM(acc00, ah0, bl0); MM(acc00, al0, bh0);
            MM(acc01, ah0, bh1); MM(acc01, ah0, bl1); MM(acc01, al0, bh1);
            MM(acc10, ah1, bh0); MM(acc10, ah1, bl0); MM(acc10, al1, bh0);
            MM(acc11, ah1, bh1); MM(acc11, ah1, bl1); MM(acc11, al1, bh1);
        }
    }

    const int arow = (lane >> 4) * 4;
    #pragma unroll
    for (int nf = 0; nf < 2; ++nf) {
        const int col = n_base + wc + nf * 16 + fr;
        const float bv = bias[col];
        #pragma unroll
        for (int mf = 0; mf < 2; ++mf) {
            const f32x4 a = (nf == 0) ? (mf == 0 ? acc00 : acc10)
                                      : (mf == 0 ? acc01 : acc11);
            #pragma unroll
            for (int r = 0; r < 4; ++r) {
                const int row = m_base + wr + mf * 16 + arow + r;
                float v = fmaxf(a[r] + bv, 0.f);
                if (SPLIT_OUT) {
                    unsigned short h, l;
                    split2(v, h, l);
                    Yh[(size_t)row * ldy + col] = h;
                    Yl[(size_t)row * ldy + col] = l;
                } else {
                    Yf[(size_t)row * ldy + col] = v;
                }
            }
        }
    }
}

// ---------------------------------------------------------------------------
// Head: out[b,:] = h2[b,:] @ W3.T + b3
// ---------------------------------------------------------------------------
__global__ __launch_bounds__(256) void head_kernel(
    const float* __restrict__ h2, const float* __restrict__ W3,
    const float* __restrict__ b3, float* __restrict__ out)
{
    const int b = blockIdx.x;
    const int t = threadIdx.x;
    const float* row = h2 + (size_t)b * REP_N;

    float a0 = 0.f, a1 = 0.f, a2 = 0.f, a3 = 0.f;
    for (int k = t; k < REP_N; k += 256) {
        float x = row[k];
        a0 = fmaf(x, W3[k],             a0);
        a1 = fmaf(x, W3[REP_N + k],     a1);
        a2 = fmaf(x, W3[2 * REP_N + k], a2);
        a3 = fmaf(x, W3[3 * REP_N + k], a3);
    }
    #pragma unroll
    for (int off = 32; off > 0; off >>= 1) {
        a0 += __shfl_down(a0, off);
        a1 += __shfl_down(a1, off);
        a2 += __shfl_down(a2, off);
        a3 += __shfl_down(a3, off);
    }
    __shared__ float red[4][4];
    int wid = t >> 6, lane = t & 63;
    if (lane == 0) { red[wid][0] = a0; red[wid][1] = a1; red[wid][2] = a2; red[wid][3] = a3; }
    __syncthreads();
    if (t < 4) {
        out[b * 4 + t] = red[0][t] + red[1][t] + red[2][t] + red[3][t] + b3[t];
    }
}

extern "C" void kernel_launch(void* const* d_in, const int* in_sizes, int n_in,
                              void* d_out, int out_size, void* d_ws, size_t ws_size,
                              hipStream_t stream) {
    const float* p1 = (const float*)d_in[0];
    const float* p2 = (const float*)d_in[1];
    const float* W1 = (const float*)d_in[2];
    const float* b1 = (const float*)d_in[3];
    const float* W2 = (const float*)d_in[4];
    const float* b2 = (const float*)d_in[5];
    const float* W3 = (const float*)d_in[6];
    const float* b3 = (const float*)d_in[7];
    float* out = (float*)d_out;

    char* ws = (char*)d_ws;
    unsigned short* xh  = (unsigned short*)(ws + 0);         // 1.31 MB
    unsigned short* xl  = (unsigned short*)(ws + 1310720);   // 1.31 MB
    unsigned short* w1h = (unsigned short*)(ws + 2621440);   // 1.31 MB
    unsigned short* w1l = (unsigned short*)(ws + 3932160);   // 1.31 MB
    float*          h2  = (float*)(ws + 0);                  // 4.19 MB (reuse after GEMM1)
    unsigned short* h1h = (unsigned short*)(ws + 5242880);   // 2.10 MB
    unsigned short* h1l = (unsigned short*)(ws + 7340032);   // 2.10 MB
    unsigned short* w2h = (unsigned short*)(ws + 9437184);   // 2.10 MB
    unsigned short* w2l = (unsigned short*)(ws + 11534336);  // 2.10 MB

    corr_gram_kernel<<<BATCH, 256, 0, stream>>>(p1, p2, xh, xl);
    prep_w1_kernel<<<(REP_N * KPAD) / 256, 256, 0, stream>>>(W1, w1h, w1l);
    prep_w2_kernel<<<(REP_N * REP_N) / (256 * 4), 256, 0, stream>>>(W2, w2h, w2l);

    gemm_mfma<true><<<dim3(16, 16), 256, 0, stream>>>(
        xh, xl, KPAD, w1h, w1l, KPAD, b1, KPAD,
        (float*)nullptr, h1h, h1l, REP_N);

    gemm_mfma<false><<<dim3(16, 16), 256, 0, stream>>>(
        h1h, h1l, REP_N, w2h, w2l, REP_N, b2, REP_N,
        h2, (unsigned short*)nullptr, (unsigned short*)nullptr, REP_N);

    head_kernel<<<BATCH, 256, 0, stream>>>(h2, W3, b3, out);
}

// Round 4
// 67.660 us; speedup vs baseline: 2.0280x; 1.0083x over previous
//
#include <hip/hip_runtime.h>

// Problem constants
#define BATCH 1024
#define RR    49        // 7*7 spatial
#define SP    12544     // 256*49 per-batch patch elems; also FLAT
#define KVALID 625      // nonzero correlation outputs per batch
#define KPAD   640      // padded K for GEMM1
#define REP_N  1024

typedef __attribute__((ext_vector_type(4))) float f32x4;
typedef __attribute__((ext_vector_type(8))) short s16x8;   // 8 bf16 (4 VGPRs)

// ---- bf16 split helpers ----
__device__ __forceinline__ unsigned short f2bf_rne(float f) {
    unsigned int u = __float_as_uint(f);
    unsigned int r = u + 0x7FFFu + ((u >> 16) & 1u);
    return (unsigned short)(r >> 16);
}
__device__ __forceinline__ float bf2f(unsigned short h) {
    return __uint_as_float(((unsigned int)h) << 16);
}
__device__ __forceinline__ void split2(float v, unsigned short& h, unsigned short& l) {
    h = f2bf_rne(v);
    l = f2bf_rne(v - bf2f(h));
}
// Pack two floats to bf16 pair (dst.lo16 = bf16(a), dst.hi16 = bf16(b)).
__device__ __forceinline__ unsigned int cvtpk_bf16(float a, float b) {
    unsigned int r;
    asm("v_cvt_pk_bf16_f32 %0, %1, %2" : "=v"(r) : "v"(a), "v"(b));
    return r;
}

// Decode index u in [0,25) -> (i, d), i,d in [0,7), i+d even.
__device__ __forceinline__ void dec25(int u, int& i, int& d) {
    int ii = (u >= 4) + (u >= 7) + (u >= 11) + (u >= 14) + (u >= 18) + (u >= 21);
    int cum = (7 * ii + 1) >> 1;
    i = ii;
    d = 2 * (u - cum) + (ii & 1);
}
// Encode (i,d) -> [0,25), inverse of dec25.
__device__ __forceinline__ int enc25(int i, int d) {
    return ((7 * i + 1) >> 1) + ((d - (i & 1)) >> 1);
}

// Compact index a in [0,640) -> flat column into W1's FLAT dim (a>=625 unused).
__device__ __forceinline__ int kflat_of(int a) {
    int ar = a / 25, ac = a % 25;
    int i, dy, j, dx;
    dec25(ar, i, dy);
    dec25(ac, j, dx);
    int pi = (dy + 16 - i) >> 1;
    int pj = (dx + 16 - j) >> 1;
    return (pi * 16 + pj) * 49 + i * 7 + j;
}

#define MM(d, a, b) d = __builtin_amdgcn_mfma_f32_16x16x32_bf16(a, b, d, 0, 0, 0)

// ---------------------------------------------------------------------------
// Kernel 1: correlation as per-batch Gram matrix via MFMA, software-pipelined.
// G[s1,s2] = sum_c p1[c,s1]*p2[c,s2]; valid outputs have (i+dy),(j+dx) even.
// Per chunk: stage 64 channels of p1^T/p2^T as split-bf16 into LDS, 24 MFMAs.
// Register prefetch: chunk cc+1's global loads issue after barrier B of cc,
// hiding L2/HBM latency under the MFMA phase.
// ---------------------------------------------------------------------------
__global__ __launch_bounds__(256) void corr_gram_kernel(
    const float* __restrict__ p1, const float* __restrict__ p2,
    unsigned short* __restrict__ xh, unsigned short* __restrict__ xl)
{
    __shared__ unsigned short Ah[64][72];
    __shared__ unsigned short Al[64][72];
    __shared__ unsigned short Bh[64][72];
    __shared__ unsigned short Bl[64][72];

    const int b = blockIdx.x;
    const int t = threadIdx.x;
    const float* P1 = p1 + (size_t)b * SP;
    const float* P2 = p2 + (size_t)b * SP;

    // ---- per-thread job table (4 job slots; 784 = 2 tensors x 8 cg x 49 s) ----
    const float* jsrc[4];
    unsigned short* jH[4];
    unsigned short* jL[4];
    bool jv[4];
    #pragma unroll
    for (int q = 0; q < 4; ++q) {
        int j = t + q * 256;
        jv[q] = (j < 784);
        int j2 = jv[q] ? j : 0;
        int isB = (j2 >= 392);
        int jj = j2 - isB * 392;
        int cg = jj / 49;
        int s  = jj - cg * 49;
        jsrc[q] = (isB ? P2 : P1) + cg * 8 * 49 + s;
        jH[q] = (isB ? &Bh[0][0] : &Ah[0][0]) + s * 72 + cg * 8;
        jL[q] = (isB ? &Bl[0][0] : &Al[0][0]) + s * 72 + cg * 8;
    }

    const int wv   = t >> 6;
    const int lane = t & 63;
    const int wr = (wv >> 1) * 32;
    const int wc = (wv & 1) * 32;
    const int fr = lane & 15;
    const int fg = (lane >> 4) * 8;

    float pf[4][8];
    // prefetch chunk 0
    #pragma unroll
    for (int q = 0; q < 4; ++q) {
        if (jv[q]) {
            #pragma unroll
            for (int i = 0; i < 8; ++i) pf[q][i] = jsrc[q][i * 49];
        }
    }

    f32x4 acc00 = {}, acc01 = {}, acc10 = {}, acc11 = {};

    for (int cc = 0; cc < 4; ++cc) {
        __syncthreads();   // A: prev chunk's MFMA readers done (also drains loads)

        // split + write LDS from prefetched regs
        #pragma unroll
        for (int q = 0; q < 4; ++q) {
            if (jv[q]) {
                s16x8 hv, lv;
                unsigned int* hp = (unsigned int*)&hv;
                unsigned int* lp = (unsigned int*)&lv;
                #pragma unroll
                for (int i = 0; i < 4; ++i) {
                    float v0 = pf[q][2 * i], v1 = pf[q][2 * i + 1];
                    unsigned int ph = cvtpk_bf16(v0, v1);
                    float h0 = __uint_as_float(ph << 16);
                    float h1 = __uint_as_float(ph & 0xFFFF0000u);
                    unsigned int pl = cvtpk_bf16(v0 - h0, v1 - h1);
                    hp[i] = ph; lp[i] = pl;
                }
                *(s16x8*)jH[q] = hv;
                *(s16x8*)jL[q] = lv;
            }
        }
        __syncthreads();   // B: tiles ready

        // issue next chunk's loads (after B so the barrier doesn't drain them)
        if (cc < 3) {
            const int off = (cc + 1) * 64 * 49;
            #pragma unroll
            for (int q = 0; q < 4; ++q) {
                if (jv[q]) {
                    #pragma unroll
                    for (int i = 0; i < 8; ++i) pf[q][i] = jsrc[q][off + i * 49];
                }
            }
        }

        // MFMA phase on current tiles
        #pragma unroll
        for (int ks = 0; ks < 2; ++ks) {
            const int ko = ks * 32 + fg;
            s16x8 ah0 = *(const s16x8*)&Ah[wr + fr][ko];
            s16x8 ah1 = *(const s16x8*)&Ah[wr + 16 + fr][ko];
            s16x8 al0 = *(const s16x8*)&Al[wr + fr][ko];
            s16x8 al1 = *(const s16x8*)&Al[wr + 16 + fr][ko];
            s16x8 bh0 = *(const s16x8*)&Bh[wc + fr][ko];
            s16x8 bh1 = *(const s16x8*)&Bh[wc + 16 + fr][ko];
            s16x8 bl0 = *(const s16x8*)&Bl[wc + fr][ko];
            s16x8 bl1 = *(const s16x8*)&Bl[wc + 16 + fr][ko];

            MM(acc00, ah0, bh0); MM(acc00, ah0, bl0); MM(acc00, al0, bh0);
            MM(acc01, ah0, bh1); MM(acc01, ah0, bl1); MM(acc01, al0, bh1);
            MM(acc10, ah1, bh0); MM(acc10, ah1, bl0); MM(acc10, al1, bh0);
            MM(acc11, ah1, bh1); MM(acc11, ah1, bl1); MM(acc11, al1, bh1);
        }
    }

    // Zero the padded tail of x
    if (t < KPAD - KVALID) {
        xh[(size_t)b * KPAD + KVALID + t] = 0;
        xl[(size_t)b * KPAD + KVALID + t] = 0;
    }

    // Epilogue: C/D layout col = lane&15, row = 4*(lane>>4)+reg.
    unsigned short* rh = xh + (size_t)b * KPAD;
    unsigned short* rl = xl + (size_t)b * KPAD;
    const int arow = (lane >> 4) * 4;
    #pragma unroll
    for (int nf = 0; nf < 2; ++nf) {
        const int n = wc + nf * 16 + fr;            // s2 = dy*7+dx
        #pragma unroll
        for (int mf = 0; mf < 2; ++mf) {
            const f32x4 a = (nf == 0) ? (mf == 0 ? acc00 : acc10)
                                      : (mf == 0 ? acc01 : acc11);
            #pragma unroll
            for (int r = 0; r < 4; ++r) {
                const int m = wr + mf * 16 + arow + r;   // s1 = i*7+j
                if (m < RR && n < RR) {
                    const int i  = m / 7, jj = m - i * 7;
                    const int dy = n / 7, dx = n - dy * 7;
                    if ((((i + dy) | (jj + dx)) & 1) == 0) {
                        const int aidx = enc25(i, dy) * 25 + enc25(jj, dx);
                        unsigned short h, l;
                        split2(a[r], h, l);
                        rh[aidx] = h; rl[aidx] = l;
                    }
                }
            }
        }
    }
}

// ---------------------------------------------------------------------------
// Prep: gather W1 columns + split  -> w1h/w1l [REP_N x KPAD]
// ---------------------------------------------------------------------------
__global__ __launch_bounds__(256) void prep_w1_kernel(
    const float* __restrict__ W1,
    unsigned short* __restrict__ wh, unsigned short* __restrict__ wl)
{
    int idx = blockIdx.x * 256 + threadIdx.x;   // over REP_N*KPAD
    int n = idx / KPAD, a = idx - n * KPAD;
    float v = 0.f;
    if (a < KVALID) v = W1[(size_t)n * SP + kflat_of(a)];
    unsigned short h, l;
    split2(v, h, l);
    wh[idx] = h; wl[idx] = l;
}

// ---------------------------------------------------------------------------
// Prep: split W2 -> w2h/w2l [REP_N x REP_N]
// ---------------------------------------------------------------------------
__global__ __launch_bounds__(256) void prep_w2_kernel(
    const float* __restrict__ W2,
    unsigned short* __restrict__ wh, unsigned short* __restrict__ wl)
{
    int idx = (blockIdx.x * 256 + threadIdx.x) * 4;
    float4 v = *(const float4*)&W2[idx];
    unsigned short h0, l0, h1, l1, h2, l2, h3, l3;
    split2(v.x, h0, l0); split2(v.y, h1, l1);
    split2(v.z, h2, l2); split2(v.w, h3, l3);
    ushort4 hv = make_ushort4(h0, h1, h2, h3);
    ushort4 lv = make_ushort4(l0, l1, l2, l3);
    *(ushort4*)&wh[idx] = hv;
    *(ushort4*)&wl[idx] = lv;
}

// ---------------------------------------------------------------------------
// MFMA GEMM: Y[m,n] = relu( sum_k X[m,k]*W[n,k] + bias[n] )
// X,W as bf16 hi/lo planes; products hh + hl + lh. 64x64 tile, BK=64,
// 4 waves (2x2), each wave 32x32 = 2x2 16x16x32 fragments.
// ---------------------------------------------------------------------------
template<bool SPLIT_OUT>
__global__ __launch_bounds__(256) void gemm_mfma(
    const unsigned short* __restrict__ Xh, const unsigned short* __restrict__ Xl, int ldx,
    const unsigned short* __restrict__ Wh, const unsigned short* __restrict__ Wl, int ldw,
    const float* __restrict__ bias, int K,
    float* __restrict__ Yf, unsigned short* __restrict__ Yh, unsigned short* __restrict__ Yl,
    int ldy)
{
    __shared__ unsigned short As[2][64][72];
    __shared__ unsigned short Bs[2][64][72];

    const int t = threadIdx.x;
    const int m_base = blockIdx.y * 64;
    const int n_base = blockIdx.x * 64;

    const int trow = t >> 2;
    const int tc   = (t & 3) * 8;

    const unsigned short* xh_p = Xh + (size_t)(m_base + trow) * ldx + tc;
    const unsigned short* xl_p = Xl + (size_t)(m_base + trow) * ldx + tc;
    const unsigned short* wh_p = Wh + (size_t)(n_base + trow) * ldw + tc;
    const unsigned short* wl_p = Wl + (size_t)(n_base + trow) * ldw + tc;

    const int wv   = t >> 6;
    const int lane = t & 63;
    const int wr = (wv >> 1) * 32;
    const int wc = (wv & 1) * 32;
    const int fr = lane & 15;
    const int fg = (lane >> 4) * 8;

    f32x4 acc00 = {}, acc01 = {}, acc10 = {}, acc11 = {};

    for (int k0 = 0; k0 < K; k0 += 64) {
        s16x8 vxh0 = *(const s16x8*)(xh_p + k0);
        s16x8 vxh1 = *(const s16x8*)(xh_p + k0 + 32);
        s16x8 vxl0 = *(const s16x8*)(xl_p + k0);
        s16x8 vxl1 = *(const s16x8*)(xl_p + k0 + 32);
        s16x8 vwh0 = *(const s16x8*)(wh_p + k0);
        s16x8 vwh1 = *(const s16x8*)(wh_p + k0 + 32);
        s16x8 vwl0 = *(const s16x8*)(wl_p + k0);
        s16x8 vwl1 = *(const s16x8*)(wl_p + k0 + 32);
        __syncthreads();
        *(s16x8*)&As[0][trow][tc]      = vxh0;
        *(s16x8*)&As[0][trow][tc + 32] = vxh1;
        *(s16x8*)&As[1][trow][tc]      = vxl0;
        *(s16x8*)&As[1][trow][tc + 32] = vxl1;
        *(s16x8*)&Bs[0][trow][tc]      = vwh0;
        *(s16x8*)&Bs[0][trow][tc + 32] = vwh1;
        *(s16x8*)&Bs[1][trow][tc]      = vwl0;
        *(s16x8*)&Bs[1][trow][tc + 32] = vwl1;
        __syncthreads();

        #pragma unroll
        for (int ks = 0; ks < 2; ++ks) {
            const int ko = ks * 32 + fg;
            s16x8 ah0 = *(const s16x8*)&As[0][wr + fr][ko];
            s16x8 ah1 = *(const s16x8*)&As[0][wr + 16 + fr][ko];
            s16x8 al0 = *(const s16x8*)&As[1][wr + fr][ko];
            s16x8 al1 = *(const s16x8*)&As[1][wr + 16 + fr][ko];
            s16x8 bh0 = *(const s16x8*)&Bs[0][wc + fr][ko];
            s16x8 bh1 = *(const s16x8*)&Bs[0][wc + 16 + fr][ko];
            s16x8 bl0 = *(const s16x8*)&Bs[1][wc + fr][ko];
            s16x8 bl1 = *(const s16x8*)&Bs[1][wc + 16 + fr][ko];

            MM(acc00, ah0, bh0); MM(acc00, ah0, bl0); MM(acc00, al0, bh0);
            MM(acc01, ah0, bh1); MM(acc01, ah0, bl1); MM(acc01, al0, bh1);
            MM(acc10, ah1, bh0); MM(acc10, ah1, bl0); MM(acc10, al1, bh0);
            MM(acc11, ah1, bh1); MM(acc11, ah1, bl1); MM(acc11, al1, bh1);
        }
    }

    const int arow = (lane >> 4) * 4;
    #pragma unroll
    for (int nf = 0; nf < 2; ++nf) {
        const int col = n_base + wc + nf * 16 + fr;
        const float bv = bias[col];
        #pragma unroll
        for (int mf = 0; mf < 2; ++mf) {
            const f32x4 a = (nf == 0) ? (mf == 0 ? acc00 : acc10)
                                      : (mf == 0 ? acc01 : acc11);
            #pragma unroll
            for (int r = 0; r < 4; ++r) {
                const int row = m_base + wr + mf * 16 + arow + r;
                float v = fmaxf(a[r] + bv, 0.f);
                if (SPLIT_OUT) {
                    unsigned short h, l;
                    split2(v, h, l);
                    Yh[(size_t)row * ldy + col] = h;
                    Yl[(size_t)row * ldy + col] = l;
                } else {
                    Yf[(size_t)row * ldy + col] = v;
                }
            }
        }
    }
}

// ---------------------------------------------------------------------------
// Head: out[b,:] = h2[b,:] @ W3.T + b3
// ---------------------------------------------------------------------------
__global__ __launch_bounds__(256) void head_kernel(
    const float* __restrict__ h2, const float* __restrict__ W3,
    const float* __restrict__ b3, float* __restrict__ out)
{
    const int b = blockIdx.x;
    const int t = threadIdx.x;
    const float* row = h2 + (size_t)b * REP_N;

    float a0 = 0.f, a1 = 0.f, a2 = 0.f, a3 = 0.f;
    for (int k = t; k < REP_N; k += 256) {
        float x = row[k];
        a0 = fmaf(x, W3[k],             a0);
        a1 = fmaf(x, W3[REP_N + k],     a1);
        a2 = fmaf(x, W3[2 * REP_N + k], a2);
        a3 = fmaf(x, W3[3 * REP_N + k], a3);
    }
    #pragma unroll
    for (int off = 32; off > 0; off >>= 1) {
        a0 += __shfl_down(a0, off);
        a1 += __shfl_down(a1, off);
        a2 += __shfl_down(a2, off);
        a3 += __shfl_down(a3, off);
    }
    __shared__ float red[4][4];
    int wid = t >> 6, lane = t & 63;
    if (lane == 0) { red[wid][0] = a0; red[wid][1] = a1; red[wid][2] = a2; red[wid][3] = a3; }
    __syncthreads();
    if (t < 4) {
        out[b * 4 + t] = red[0][t] + red[1][t] + red[2][t] + red[3][t] + b3[t];
    }
}

extern "C" void kernel_launch(void* const* d_in, const int* in_sizes, int n_in,
                              void* d_out, int out_size, void* d_ws, size_t ws_size,
                              hipStream_t stream) {
    const float* p1 = (const float*)d_in[0];
    const float* p2 = (const float*)d_in[1];
    const float* W1 = (const float*)d_in[2];
    const float* b1 = (const float*)d_in[3];
    const float* W2 = (const float*)d_in[4];
    const float* b2 = (const float*)d_in[5];
    const float* W3 = (const float*)d_in[6];
    const float* b3 = (const float*)d_in[7];
    float* out = (float*)d_out;

    char* ws = (char*)d_ws;
    unsigned short* xh  = (unsigned short*)(ws + 0);         // 1.31 MB
    unsigned short* xl  = (unsigned short*)(ws + 1310720);   // 1.31 MB
    unsigned short* w1h = (unsigned short*)(ws + 2621440);   // 1.31 MB
    unsigned short* w1l = (unsigned short*)(ws + 3932160);   // 1.31 MB
    float*          h2  = (float*)(ws + 0);                  // 4.19 MB (reuse after GEMM1)
    unsigned short* h1h = (unsigned short*)(ws + 5242880);   // 2.10 MB
    unsigned short* h1l = (unsigned short*)(ws + 7340032);   // 2.10 MB
    unsigned short* w2h = (unsigned short*)(ws + 9437184);   // 2.10 MB
    unsigned short* w2l = (unsigned short*)(ws + 11534336);  // 2.10 MB

    corr_gram_kernel<<<BATCH, 256, 0, stream>>>(p1, p2, xh, xl);
    prep_w1_kernel<<<(REP_N * KPAD) / 256, 256, 0, stream>>>(W1, w1h, w1l);
    prep_w2_kernel<<<(REP_N * REP_N) / (256 * 4), 256, 0, stream>>>(W2, w2h, w2l);

    gemm_mfma<true><<<dim3(16, 16), 256, 0, stream>>>(
        xh, xl, KPAD, w1h, w1l, KPAD, b1, KPAD,
        (float*)nullptr, h1h, h1l, REP_N);

    gemm_mfma<false><<<dim3(16, 16), 256, 0, stream>>>(
        h1h, h1l, REP_N, w2h, w2l, REP_N, b2, REP_N,
        h2, (unsigned short*)nullptr, (unsigned short*)nullptr, REP_N);

    head_kernel<<<BATCH, 256, 0, stream>>>(h2, W3, b3, out);
}

// Round 5
// 66.716 us; speedup vs baseline: 2.0567x; 1.0142x over previous
//
#include <hip/hip_runtime.h>

// Problem constants
#define BATCH 1024
#define RR    49        // 7*7 spatial
#define SP    12544     // 256*49 per-batch patch elems; also FLAT
#define KVALID 625      // nonzero correlation outputs per batch
#define KPAD   640      // padded K for GEMM1
#define REP_N  1024

typedef __attribute__((ext_vector_type(4))) float f32x4;
typedef __attribute__((ext_vector_type(8))) short s16x8;   // 8 bf16 (4 VGPRs)

// ---- bf16 split helpers ----
__device__ __forceinline__ unsigned short f2bf_rne(float f) {
    unsigned int u = __float_as_uint(f);
    unsigned int r = u + 0x7FFFu + ((u >> 16) & 1u);
    return (unsigned short)(r >> 16);
}
__device__ __forceinline__ float bf2f(unsigned short h) {
    return __uint_as_float(((unsigned int)h) << 16);
}
__device__ __forceinline__ void split2(float v, unsigned short& h, unsigned short& l) {
    h = f2bf_rne(v);
    l = f2bf_rne(v - bf2f(h));
}
// Pack two floats to bf16 pair (dst.lo16 = bf16(a), dst.hi16 = bf16(b)).
// Verified numerically in R4 (absmax unchanged).
__device__ __forceinline__ unsigned int cvtpk_bf16(float a, float b) {
    unsigned int r;
    asm("v_cvt_pk_bf16_f32 %0, %1, %2" : "=v"(r) : "v"(a), "v"(b));
    return r;
}
// Split 8 floats -> hi/lo s16x8 fragments.
__device__ __forceinline__ void cvt8(const float* v, s16x8& hv, s16x8& lv) {
    unsigned int* hp = (unsigned int*)&hv;
    unsigned int* lp = (unsigned int*)&lv;
    #pragma unroll
    for (int i = 0; i < 4; ++i) {
        float v0 = v[2 * i], v1 = v[2 * i + 1];
        unsigned int ph = cvtpk_bf16(v0, v1);
        float h0 = __uint_as_float(ph << 16);
        float h1 = __uint_as_float(ph & 0xFFFF0000u);
        unsigned int pl = cvtpk_bf16(v0 - h0, v1 - h1);
        hp[i] = ph; lp[i] = pl;
    }
}

// Decode index u in [0,25) -> (i, d), i,d in [0,7), i+d even.
__device__ __forceinline__ void dec25(int u, int& i, int& d) {
    int ii = (u >= 4) + (u >= 7) + (u >= 11) + (u >= 14) + (u >= 18) + (u >= 21);
    int cum = (7 * ii + 1) >> 1;
    i = ii;
    d = 2 * (u - cum) + (ii & 1);
}
// Encode (i,d) -> [0,25), inverse of dec25.
__device__ __forceinline__ int enc25(int i, int d) {
    return ((7 * i + 1) >> 1) + ((d - (i & 1)) >> 1);
}

// Compact index a in [0,640) -> flat column into W1's FLAT dim (a>=625 unused).
__device__ __forceinline__ int kflat_of(int a) {
    int ar = a / 25, ac = a % 25;
    int i, dy, j, dx;
    dec25(ar, i, dy);
    dec25(ac, j, dx);
    int pi = (dy + 16 - i) >> 1;
    int pj = (dx + 16 - j) >> 1;
    return (pi * 16 + pj) * 49 + i * 7 + j;
}

#define MM(d, a, b) d = __builtin_amdgcn_mfma_f32_16x16x32_bf16(a, b, d, 0, 0, 0)

// ---------------------------------------------------------------------------
// Kernel 1: correlation as per-batch Gram matrix, LDS-free / barrier-free.
// One block = one batch; 4 waves, each owns a 32x32 quadrant of the 64x64
// (49x49 used) Gram tile. Fragments are gathered DIRECTLY from global at
// 196B stride (coalesced across the 16 contiguous-s lanes), split to
// hi/lo bf16 in-register, and fed to MFMA. No staging LDS, no barriers.
// Rows/cols 49..63 clamp their source address to s=48; their outputs are
// discarded by the epilogue mask.
// ---------------------------------------------------------------------------
__global__ __launch_bounds__(256) void corr_gram_kernel(
    const float* __restrict__ p1, const float* __restrict__ p2,
    unsigned short* __restrict__ xh, unsigned short* __restrict__ xl)
{
    __shared__ unsigned short SXh[KPAD];   // compact-output staging (2.5 KB)
    __shared__ unsigned short SXl[KPAD];

    const int b = blockIdx.x;
    const int t = threadIdx.x;
    const float* P1 = p1 + (size_t)b * SP;
    const float* P2 = p2 + (size_t)b * SP;

    const int wv   = t >> 6;
    const int lane = t & 63;
    const int wr = (wv >> 1) * 32;   // wave row offset (s1)
    const int wc = (wv & 1) * 32;    // wave col offset (s2)
    const int fr = lane & 15;
    const int fg = (lane >> 4) * 8;  // k-offset within 32-chunk: 0,8,16,24

    // Per-lane source spatial columns (clamped to stay in-bounds).
    const int sa0 = wr + fr;
    const int sa1 = min(wr + 16 + fr, 48);
    const int sb0 = wc + fr;
    const int sb1 = min(wc + 16 + fr, 48);

    const float* pa0 = P1 + fg * 49 + sa0;
    const float* pa1 = P1 + fg * 49 + sa1;
    const float* pb0 = P2 + fg * 49 + sb0;
    const float* pb1 = P2 + fg * 49 + sb1;

    // zero output staging
    for (int i = t; i < KPAD; i += 256) { SXh[i] = 0; SXl[i] = 0; }

    f32x4 acc00 = {}, acc01 = {}, acc10 = {}, acc11 = {};

    #pragma unroll
    for (int cc = 0; cc < 4; ++cc) {
        #pragma unroll
        for (int ks = 0; ks < 2; ++ks) {
            const int co = (cc * 64 + ks * 32) * 49;
            float a0f[8], a1f[8], b0f[8], b1f[8];
            #pragma unroll
            for (int i = 0; i < 8; ++i) {
                a0f[i] = pa0[co + i * 49];
                a1f[i] = pa1[co + i * 49];
                b0f[i] = pb0[co + i * 49];
                b1f[i] = pb1[co + i * 49];
            }
            s16x8 ah0, al0, ah1, al1, bh0, bl0, bh1, bl1;
            cvt8(a0f, ah0, al0);
            cvt8(a1f, ah1, al1);
            cvt8(b0f, bh0, bl0);
            cvt8(b1f, bh1, bl1);

            MM(acc00, ah0, bh0); MM(acc00, ah0, bl0); MM(acc00, al0, bh0);
            MM(acc01, ah0, bh1); MM(acc01, ah0, bl1); MM(acc01, al0, bh1);
            MM(acc10, ah1, bh0); MM(acc10, ah1, bl0); MM(acc10, al1, bh0);
            MM(acc11, ah1, bh1); MM(acc11, ah1, bl1); MM(acc11, al1, bh1);
        }
    }

    // Epilogue: scatter valid entries into LDS (C/D layout: col = lane&15,
    // row = 4*(lane>>4)+reg), then dump contiguously.
    const int arow = (lane >> 4) * 4;
    #pragma unroll
    for (int nf = 0; nf < 2; ++nf) {
        const int n = wc + nf * 16 + fr;            // s2 = dy*7+dx
        #pragma unroll
        for (int mf = 0; mf < 2; ++mf) {
            const f32x4 a = (nf == 0) ? (mf == 0 ? acc00 : acc10)
                                      : (mf == 0 ? acc01 : acc11);
            #pragma unroll
            for (int r = 0; r < 4; ++r) {
                const int m = wr + mf * 16 + arow + r;   // s1 = i*7+j
                if (m < RR && n < RR) {
                    const int i  = m / 7, jj = m - i * 7;
                    const int dy = n / 7, dx = n - dy * 7;
                    if ((((i + dy) | (jj + dx)) & 1) == 0) {
                        const int aidx = enc25(i, dy) * 25 + enc25(jj, dx);
                        unsigned short h, l;
                        split2(a[r], h, l);
                        SXh[aidx] = h; SXl[aidx] = l;
                    }
                }
            }
        }
    }
    __syncthreads();

    unsigned int* rh = (unsigned int*)(xh + (size_t)b * KPAD);
    unsigned int* rl = (unsigned int*)(xl + (size_t)b * KPAD);
    const unsigned int* sh = (const unsigned int*)SXh;
    const unsigned int* sl = (const unsigned int*)SXl;
    for (int i = t; i < KPAD / 2; i += 256) { rh[i] = sh[i]; rl[i] = sl[i]; }
}

// ---------------------------------------------------------------------------
// Prep: gather W1 columns + split  -> w1h/w1l [REP_N x KPAD]
// ---------------------------------------------------------------------------
__global__ __launch_bounds__(256) void prep_w1_kernel(
    const float* __restrict__ W1,
    unsigned short* __restrict__ wh, unsigned short* __restrict__ wl)
{
    int idx = blockIdx.x * 256 + threadIdx.x;   // over REP_N*KPAD
    int n = idx / KPAD, a = idx - n * KPAD;
    float v = 0.f;
    if (a < KVALID) v = W1[(size_t)n * SP + kflat_of(a)];
    unsigned short h, l;
    split2(v, h, l);
    wh[idx] = h; wl[idx] = l;
}

// ---------------------------------------------------------------------------
// Prep: split W2 -> w2h/w2l [REP_N x REP_N]
// ---------------------------------------------------------------------------
__global__ __launch_bounds__(256) void prep_w2_kernel(
    const float* __restrict__ W2,
    unsigned short* __restrict__ wh, unsigned short* __restrict__ wl)
{
    int idx = (blockIdx.x * 256 + threadIdx.x) * 4;
    float4 v = *(const float4*)&W2[idx];
    unsigned short h0, l0, h1, l1, h2, l2, h3, l3;
    split2(v.x, h0, l0); split2(v.y, h1, l1);
    split2(v.z, h2, l2); split2(v.w, h3, l3);
    ushort4 hv = make_ushort4(h0, h1, h2, h3);
    ushort4 lv = make_ushort4(l0, l1, l2, l3);
    *(ushort4*)&wh[idx] = hv;
    *(ushort4*)&wl[idx] = lv;
}

// ---------------------------------------------------------------------------
// MFMA GEMM: Y[m,n] = relu( sum_k X[m,k]*W[n,k] + bias[n] )
// X,W as bf16 hi/lo planes; products hh + hl + lh. 64x64 tile, BK=64,
// 4 waves (2x2), each wave 32x32 = 2x2 16x16x32 fragments.
// ---------------------------------------------------------------------------
template<bool SPLIT_OUT>
__global__ __launch_bounds__(256) void gemm_mfma(
    const unsigned short* __restrict__ Xh, const unsigned short* __restrict__ Xl, int ldx,
    const unsigned short* __restrict__ Wh, const unsigned short* __restrict__ Wl, int ldw,
    const float* __restrict__ bias, int K,
    float* __restrict__ Yf, unsigned short* __restrict__ Yh, unsigned short* __restrict__ Yl,
    int ldy)
{
    __shared__ unsigned short As[2][64][72];
    __shared__ unsigned short Bs[2][64][72];

    const int t = threadIdx.x;
    const int m_base = blockIdx.y * 64;
    const int n_base = blockIdx.x * 64;

    const int trow = t >> 2;
    const int tc   = (t & 3) * 8;

    const unsigned short* xh_p = Xh + (size_t)(m_base + trow) * ldx + tc;
    const unsigned short* xl_p = Xl + (size_t)(m_base + trow) * ldx + tc;
    const unsigned short* wh_p = Wh + (size_t)(n_base + trow) * ldw + tc;
    const unsigned short* wl_p = Wl + (size_t)(n_base + trow) * ldw + tc;

    const int wv   = t >> 6;
    const int lane = t & 63;
    const int wr = (wv >> 1) * 32;
    const int wc = (wv & 1) * 32;
    const int fr = lane & 15;
    const int fg = (lane >> 4) * 8;

    f32x4 acc00 = {}, acc01 = {}, acc10 = {}, acc11 = {};

    for (int k0 = 0; k0 < K; k0 += 64) {
        s16x8 vxh0 = *(const s16x8*)(xh_p + k0);
        s16x8 vxh1 = *(const s16x8*)(xh_p + k0 + 32);
        s16x8 vxl0 = *(const s16x8*)(xl_p + k0);
        s16x8 vxl1 = *(const s16x8*)(xl_p + k0 + 32);
        s16x8 vwh0 = *(const s16x8*)(wh_p + k0);
        s16x8 vwh1 = *(const s16x8*)(wh_p + k0 + 32);
        s16x8 vwl0 = *(const s16x8*)(wl_p + k0);
        s16x8 vwl1 = *(const s16x8*)(wl_p + k0 + 32);
        __syncthreads();
        *(s16x8*)&As[0][trow][tc]      = vxh0;
        *(s16x8*)&As[0][trow][tc + 32] = vxh1;
        *(s16x8*)&As[1][trow][tc]      = vxl0;
        *(s16x8*)&As[1][trow][tc + 32] = vxl1;
        *(s16x8*)&Bs[0][trow][tc]      = vwh0;
        *(s16x8*)&Bs[0][trow][tc + 32] = vwh1;
        *(s16x8*)&Bs[1][trow][tc]      = vwl0;
        *(s16x8*)&Bs[1][trow][tc + 32] = vwl1;
        __syncthreads();

        #pragma unroll
        for (int ks = 0; ks < 2; ++ks) {
            const int ko = ks * 32 + fg;
            s16x8 ah0 = *(const s16x8*)&As[0][wr + fr][ko];
            s16x8 ah1 = *(const s16x8*)&As[0][wr + 16 + fr][ko];
            s16x8 al0 = *(const s16x8*)&As[1][wr + fr][ko];
            s16x8 al1 = *(const s16x8*)&As[1][wr + 16 + fr][ko];
            s16x8 bh0 = *(const s16x8*)&Bs[0][wc + fr][ko];
            s16x8 bh1 = *(const s16x8*)&Bs[0][wc + 16 + fr][ko];
            s16x8 bl0 = *(const s16x8*)&Bs[1][wc + fr][ko];
            s16x8 bl1 = *(const s16x8*)&Bs[1][wc + 16 + fr][ko];

            MM(acc00, ah0, bh0); MM(acc00, ah0, bl0); MM(acc00, al0, bh0);
            MM(acc01, ah0, bh1); MM(acc01, ah0, bl1); MM(acc01, al0, bh1);
            MM(acc10, ah1, bh0); MM(acc10, ah1, bl0); MM(acc10, al1, bh0);
            MM(acc11, ah1, bh1); MM(acc11, ah1, bl1); MM(acc11, al1, bh1);
        }
    }

    const int arow = (lane >> 4) * 4;
    #pragma unroll
    for (int nf = 0; nf < 2; ++nf) {
        const int col = n_base + wc + nf * 16 + fr;
        const float bv = bias[col];
        #pragma unroll
        for (int mf = 0; mf < 2; ++mf) {
            const f32x4 a = (nf == 0) ? (mf == 0 ? acc00 : acc10)
                                      : (mf == 0 ? acc01 : acc11);
            #pragma unroll
            for (int r = 0; r < 4; ++r) {
                const int row = m_base + wr + mf * 16 + arow + r;
                float v = fmaxf(a[r] + bv, 0.f);
                if (SPLIT_OUT) {
                    unsigned short h, l;
                    split2(v, h, l);
                    Yh[(size_t)row * ldy + col] = h;
                    Yl[(size_t)row * ldy + col] = l;
                } else {
                    Yf[(size_t)row * ldy + col] = v;
                }
            }
        }
    }
}

// ---------------------------------------------------------------------------
// Head: out[b,:] = h2[b,:] @ W3.T + b3
// ---------------------------------------------------------------------------
__global__ __launch_bounds__(256) void head_kernel(
    const float* __restrict__ h2, const float* __restrict__ W3,
    const float* __restrict__ b3, float* __restrict__ out)
{
    const int b = blockIdx.x;
    const int t = threadIdx.x;
    const float* row = h2 + (size_t)b * REP_N;

    float a0 = 0.f, a1 = 0.f, a2 = 0.f, a3 = 0.f;
    for (int k = t; k < REP_N; k += 256) {
        float x = row[k];
        a0 = fmaf(x, W3[k],             a0);
        a1 = fmaf(x, W3[REP_N + k],     a1);
        a2 = fmaf(x, W3[2 * REP_N + k], a2);
        a3 = fmaf(x, W3[3 * REP_N + k], a3);
    }
    #pragma unroll
    for (int off = 32; off > 0; off >>= 1) {
        a0 += __shfl_down(a0, off);
        a1 += __shfl_down(a1, off);
        a2 += __shfl_down(a2, off);
        a3 += __shfl_down(a3, off);
    }
    __shared__ float red[4][4];
    int wid = t >> 6, lane = t & 63;
    if (lane == 0) { red[wid][0] = a0; red[wid][1] = a1; red[wid][2] = a2; red[wid][3] = a3; }
    __syncthreads();
    if (t < 4) {
        out[b * 4 + t] = red[0][t] + red[1][t] + red[2][t] + red[3][t] + b3[t];
    }
}

extern "C" void kernel_launch(void* const* d_in, const int* in_sizes, int n_in,
                              void* d_out, int out_size, void* d_ws, size_t ws_size,
                              hipStream_t stream) {
    const float* p1 = (const float*)d_in[0];
    const float* p2 = (const float*)d_in[1];
    const float* W1 = (const float*)d_in[2];
    const float* b1 = (const float*)d_in[3];
    const float* W2 = (const float*)d_in[4];
    const float* b2 = (const float*)d_in[5];
    const float* W3 = (const float*)d_in[6];
    const float* b3 = (const float*)d_in[7];
    float* out = (float*)d_out;

    char* ws = (char*)d_ws;
    unsigned short* xh  = (unsigned short*)(ws + 0);         // 1.31 MB
    unsigned short* xl  = (unsigned short*)(ws + 1310720);   // 1.31 MB
    unsigned short* w1h = (unsigned short*)(ws + 2621440);   // 1.31 MB
    unsigned short* w1l = (unsigned short*)(ws + 3932160);   // 1.31 MB
    float*          h2  = (float*)(ws + 0);                  // 4.19 MB (reuse after GEMM1)
    unsigned short* h1h = (unsigned short*)(ws + 5242880);   // 2.10 MB
    unsigned short* h1l = (unsigned short*)(ws + 7340032);   // 2.10 MB
    unsigned short* w2h = (unsigned short*)(ws + 9437184);   // 2.10 MB
    unsigned short* w2l = (unsigned short*)(ws + 11534336);  // 2.10 MB

    corr_gram_kernel<<<BATCH, 256, 0, stream>>>(p1, p2, xh, xl);
    prep_w1_kernel<<<(REP_N * KPAD) / 256, 256, 0, stream>>>(W1, w1h, w1l);
    prep_w2_kernel<<<(REP_N * REP_N) / (256 * 4), 256, 0, stream>>>(W2, w2h, w2l);

    gemm_mfma<true><<<dim3(16, 16), 256, 0, stream>>>(
        xh, xl, KPAD, w1h, w1l, KPAD, b1, KPAD,
        (float*)nullptr, h1h, h1l, REP_N);

    gemm_mfma<false><<<dim3(16, 16), 256, 0, stream>>>(
        h1h, h1l, REP_N, w2h, w2l, REP_N, b2, REP_N,
        h2, (unsigned short*)nullptr, (unsigned short*)nullptr, REP_N);

    head_kernel<<<BATCH, 256, 0, stream>>>(h2, W3, b3, out);
}